// Round 10
// baseline (187.307 us; speedup 1.0000x reference)
//
#include <hip/hip_runtime.h>
#include <hip/hip_bf16.h>
#include <math.h>

// MEASUREMENT ROUND: exact best-known (86.7 us) source; gather_norm launched
// 5x (idempotent) to expose G = gather duration via dur_us delta.

// Problem constants (match reference)
#define BB      8
#define C_CH    128
#define HH      256
#define WW      256
#define N_POS   2048
#define N_NEG   8192
#define N_ROWS  (N_POS + N_NEG)     // 10240
#define EPS_N   1e-6f

// sim tiling: block = 4 waves as 2x2, each wave 64x64 output, K=128 in 4 steps
#define NIB     (N_POS / 128)       // 16
#define NJB     (N_ROWS / 128)      // 80
#define NJSLAB      (N_ROWS / 64)   // 160 j-slabs of 64 cols (per-wave extent)
#define NJSLAB_POS  (N_POS / 64)    // 32

typedef __attribute__((ext_vector_type(8))) short bf16x8;   // 8 bf16 = 4 VGPR
typedef __attribute__((ext_vector_type(4))) float f32x4;    // MFMA C/D

// Workspace layout:
//   hi:      [N_ROWS][128] bf16   @ 0              (2.62 MB)
//   lo:      [N_ROWS][128] bf16   @ 2.62 MB        (2.62 MB)
//   partial: [NJSLAB][N_POS] f32                   (1.31 MB)
//   term:    [N_POS] f32                           (8 KB)

// ---------------------------------------------------------------------------
// Kernel 1: gather + L2-normalize + split to bf16 hi/lo. 1 row/wave (measured
// best). Lane l owns channels l and l+64.
__global__ __launch_bounds__(256) void gather_norm_kernel(
    const float* __restrict__ seg,
    const int* __restrict__ pb, const int* __restrict__ ph, const int* __restrict__ pw,
    const int* __restrict__ nb, const int* __restrict__ nh, const int* __restrict__ nw,
    __hip_bfloat16* __restrict__ hi, __hip_bfloat16* __restrict__ lo)
{
    const int wave = threadIdx.x >> 6;
    const int lane = threadIdx.x & 63;
    const int row  = blockIdx.x * 4 + wave;
    if (row >= N_ROWS) return;

    int b, h, w;
    if (row < N_POS) { b = pb[row]; h = ph[row]; w = pw[row]; }
    else { const int r = row - N_POS; b = nb[r]; h = nh[r]; w = nw[r]; }

    const size_t cs   = (size_t)HH * WW;
    const size_t base = (size_t)b * C_CH * cs + (size_t)h * WW + (size_t)w;

    const float v0 = seg[base + (size_t)lane * cs];
    const float v1 = seg[base + (size_t)(lane + 64) * cs];

    float ss = v0 * v0 + v1 * v1;
#pragma unroll
    for (int m = 1; m < 64; m <<= 1) ss += __shfl_xor(ss, m, 64);

    const float n  = fmaxf(sqrtf(ss), EPS_N);
    const float u0 = v0 / n;
    const float u1 = v1 / n;

    const __hip_bfloat16 h0 = __float2bfloat16(u0);
    const __hip_bfloat16 h1 = __float2bfloat16(u1);
    const __hip_bfloat16 l0 = __float2bfloat16(u0 - __bfloat162float(h0));
    const __hip_bfloat16 l1 = __float2bfloat16(u1 - __bfloat162float(h1));

    const size_t o = (size_t)row * C_CH + lane;
    hi[o]      = h0;  lo[o]      = l0;
    hi[o + 64] = h1;  lo[o + 64] = l1;
}

// ---------------------------------------------------------------------------
// Kernel 2: C[i][j] = dot(x_i, x_j) via 3-term split-bf16 MFMA, no LDS
// (operands L2/L3-resident). Epilogue: expf + per-row sum over the wave's 64
// cols; one write per (jslab,row) => deterministic.
__global__ __launch_bounds__(256, 2) void sim_mfma_kernel(
    const __hip_bfloat16* __restrict__ hi_, const __hip_bfloat16* __restrict__ lo_,
    float* __restrict__ partial)
{
    const ushort* __restrict__ hi = (const ushort*)hi_;
    const ushort* __restrict__ lo = (const ushort*)lo_;

    const int bid = blockIdx.x;
    const int ib  = bid / NJB;          // 0..15
    const int jb  = bid % NJB;          // 0..79  (ids sharing jb are == mod 8 -> same XCD)
    const int t    = threadIdx.x;
    const int wave = t >> 6;
    const int lane = t & 63;
    const int wy = wave >> 1;           // i-half
    const int wx = wave & 1;            // j-half

    const int iw0 = ib * 128 + wy * 64;
    const int jw0 = jb * 128 + wx * 64;

    const int lr = lane & 15;           // row/col within 16x16 tile
    const int lk = lane >> 4;           // k-chunk (8 bf16)

    f32x4 acc[4][4];
#pragma unroll
    for (int m = 0; m < 4; ++m)
#pragma unroll
        for (int n = 0; n < 4; ++n) acc[m][n] = (f32x4){0.f, 0.f, 0.f, 0.f};

#pragma unroll
    for (int ks = 0; ks < 4; ++ks) {
        const int koff = ks * 32 + lk * 8;

        bf16x8 ah[4], al[4];
#pragma unroll
        for (int m = 0; m < 4; ++m) {
            const size_t ra = (size_t)(iw0 + m * 16 + lr) * C_CH + koff;
            ah[m] = *(const bf16x8*)&hi[ra];
            al[m] = *(const bf16x8*)&lo[ra];
        }
#pragma unroll
        for (int n = 0; n < 4; ++n) {
            const size_t rb = (size_t)(jw0 + n * 16 + lr) * C_CH + koff;
            const bf16x8 bh = *(const bf16x8*)&hi[rb];
            const bf16x8 bl = *(const bf16x8*)&lo[rb];
#pragma unroll
            for (int m = 0; m < 4; ++m) {
                acc[m][n] = __builtin_amdgcn_mfma_f32_16x16x32_bf16(ah[m], bh, acc[m][n], 0, 0, 0);
                acc[m][n] = __builtin_amdgcn_mfma_f32_16x16x32_bf16(ah[m], bl, acc[m][n], 0, 0, 0);
                acc[m][n] = __builtin_amdgcn_mfma_f32_16x16x32_bf16(al[m], bh, acc[m][n], 0, 0, 0);
            }
        }
    }

    // Epilogue. C/D layout: value r of lane l = C[iw0+m*16+(l>>4)*4+r][jw0+n*16+(l&15)]
    const int jslab = jw0 >> 6;         // 0..159
#pragma unroll
    for (int m = 0; m < 4; ++m) {
        float s0 = 0.f, s1 = 0.f, s2 = 0.f, s3 = 0.f;
#pragma unroll
        for (int n = 0; n < 4; ++n) {
            s0 += expf(acc[m][n][0]);
            s1 += expf(acc[m][n][1]);
            s2 += expf(acc[m][n][2]);
            s3 += expf(acc[m][n][3]);
        }
        float s[4] = {s0, s1, s2, s3};
#pragma unroll
        for (int r = 0; r < 4; ++r) {
            float v = s[r];
            v += __shfl_xor(v, 1, 64);
            v += __shfl_xor(v, 2, 64);
            v += __shfl_xor(v, 4, 64);
            v += __shfl_xor(v, 8, 64);
            if (lr == 0) {
                const int row = iw0 + m * 16 + lk * 4 + r;
                partial[(size_t)jslab * N_POS + row] = v;
            }
        }
    }
}

// ---------------------------------------------------------------------------
// Kernel 3a: per-row reduction over the 160 j-slab partials (coalesced).
__global__ __launch_bounds__(256) void rowred_kernel(
    const float* __restrict__ partial, float* __restrict__ term)
{
    const int row = blockIdx.x * 256 + threadIdx.x;
    float P = 0.f, Nv = 0.f;
    for (int s = 0; s < NJSLAB_POS; ++s)      P  += partial[(size_t)s * N_POS + row];
    for (int s = NJSLAB_POS; s < NJSLAB; ++s) Nv += partial[(size_t)s * N_POS + row];
    const float p = P - 2.71828182845904523536f;   // remove self-sim exp(1)
    term[row] = logf(p) - logf(p + Nv);
}

// Kernel 3b: single block => deterministic final mean.
__global__ __launch_bounds__(256) void final_kernel(
    const float* __restrict__ term, float* __restrict__ out)
{
    const int t = threadIdx.x;
    float local = 0.f;
    for (int i = t; i < N_POS; i += 256) local += term[i];

    __shared__ float red[256];
    red[t] = local;
    __syncthreads();
    for (int s = 128; s > 0; s >>= 1) {
        if (t < s) red[t] += red[t + s];
        __syncthreads();
    }
    if (t == 0) out[0] = -red[0] / (float)N_POS;
}

// ---------------------------------------------------------------------------
extern "C" void kernel_launch(void* const* d_in, const int* in_sizes, int n_in,
                              void* d_out, int out_size, void* d_ws, size_t ws_size,
                              hipStream_t stream)
{
    const float* seg = (const float*)d_in[0];
    const int* pb = (const int*)d_in[1];
    const int* ph = (const int*)d_in[2];
    const int* pw = (const int*)d_in[3];
    const int* nb = (const int*)d_in[4];
    const int* nh = (const int*)d_in[5];
    const int* nw = (const int*)d_in[6];
    float* out = (float*)d_out;

    __hip_bfloat16* hi = (__hip_bfloat16*)d_ws;
    __hip_bfloat16* lo = hi + (size_t)N_ROWS * C_CH;
    float* partial = (float*)(lo + (size_t)N_ROWS * C_CH);
    float* term    = partial + (size_t)NJSLAB * N_POS;

    // MEASUREMENT: 5x idempotent gather launches => dur = base + 4*G.
    for (int rep = 0; rep < 5; ++rep) {
        gather_norm_kernel<<<dim3((N_ROWS + 3) / 4), dim3(256), 0, stream>>>(
            seg, pb, ph, pw, nb, nh, nw, hi, lo);
    }

    sim_mfma_kernel<<<dim3(NIB * NJB), dim3(256), 0, stream>>>(hi, lo, partial);

    rowred_kernel<<<dim3(N_POS / 256), dim3(256), 0, stream>>>(partial, term);
    final_kernel<<<dim3(1), dim3(256), 0, stream>>>(term, out);
}

// Round 11
// 84.825 us; speedup vs baseline: 2.2082x; 2.2082x over previous
//
#include <hip/hip_runtime.h>
#include <hip/hip_bf16.h>
#include <math.h>

// Problem constants (match reference)
#define BB      8
#define C_CH    128
#define HH      256
#define WW      256
#define N_POS   2048
#define N_NEG   8192
#define N_ROWS  (N_POS + N_NEG)     // 10240
#define EPS_N   1e-6f

// sim tiling: block = 4 waves as 2x2, each wave 64x64 output, K=128 in 4 steps
#define NIB     (N_POS / 128)       // 16
#define NJB     (N_ROWS / 128)      // 80
#define NJSLAB      (N_ROWS / 64)   // 160 j-slabs of 64 cols (per-wave extent)
#define NJSLAB_POS  (N_POS / 64)    // 32

typedef __attribute__((ext_vector_type(8))) short bf16x8;   // 8 bf16 = 4 VGPR
typedef __attribute__((ext_vector_type(4))) float f32x4;    // MFMA C/D

// Workspace layout:
//   hi:      [N_ROWS][128] bf16   @ 0              (2.62 MB)
//   lo:      [N_ROWS][128] bf16   @ 2.62 MB        (2.62 MB)
//   partial: [NJSLAB][N_POS] f32                   (1.31 MB)
//   bsum:    [8] f32                               (32 B)

// ---------------------------------------------------------------------------
// Kernel 1: gather + L2-normalize + split to bf16 hi/lo. 1 row/wave (measured
// best, G ~= 25 us). Lane l owns channels l and l+64.
__global__ __launch_bounds__(256) void gather_norm_kernel(
    const float* __restrict__ seg,
    const int* __restrict__ pb, const int* __restrict__ ph, const int* __restrict__ pw,
    const int* __restrict__ nb, const int* __restrict__ nh, const int* __restrict__ nw,
    __hip_bfloat16* __restrict__ hi, __hip_bfloat16* __restrict__ lo)
{
    const int wave = threadIdx.x >> 6;
    const int lane = threadIdx.x & 63;
    const int row  = blockIdx.x * 4 + wave;
    if (row >= N_ROWS) return;

    int b, h, w;
    if (row < N_POS) { b = pb[row]; h = ph[row]; w = pw[row]; }
    else { const int r = row - N_POS; b = nb[r]; h = nh[r]; w = nw[r]; }

    const size_t cs   = (size_t)HH * WW;
    const size_t base = (size_t)b * C_CH * cs + (size_t)h * WW + (size_t)w;

    const float v0 = seg[base + (size_t)lane * cs];
    const float v1 = seg[base + (size_t)(lane + 64) * cs];

    float ss = v0 * v0 + v1 * v1;
#pragma unroll
    for (int m = 1; m < 64; m <<= 1) ss += __shfl_xor(ss, m, 64);

    const float n  = fmaxf(sqrtf(ss), EPS_N);
    const float u0 = v0 / n;
    const float u1 = v1 / n;

    const __hip_bfloat16 h0 = __float2bfloat16(u0);
    const __hip_bfloat16 h1 = __float2bfloat16(u1);
    const __hip_bfloat16 l0 = __float2bfloat16(u0 - __bfloat162float(h0));
    const __hip_bfloat16 l1 = __float2bfloat16(u1 - __bfloat162float(h1));

    const size_t o = (size_t)row * C_CH + lane;
    hi[o]      = h0;  lo[o]      = l0;
    hi[o + 64] = h1;  lo[o + 64] = l1;
}

// ---------------------------------------------------------------------------
// Kernel 2: C[i][j] = dot(x_i, x_j) via 3-term split-bf16 MFMA, no LDS
// (operands L2/L3-resident). UNCHANGED from the 86.7 us best-known source.
__global__ __launch_bounds__(256, 2) void sim_mfma_kernel(
    const __hip_bfloat16* __restrict__ hi_, const __hip_bfloat16* __restrict__ lo_,
    float* __restrict__ partial)
{
    const ushort* __restrict__ hi = (const ushort*)hi_;
    const ushort* __restrict__ lo = (const ushort*)lo_;

    const int bid = blockIdx.x;
    const int ib  = bid / NJB;          // 0..15
    const int jb  = bid % NJB;          // 0..79  (ids sharing jb are == mod 8 -> same XCD)
    const int t    = threadIdx.x;
    const int wave = t >> 6;
    const int lane = t & 63;
    const int wy = wave >> 1;           // i-half
    const int wx = wave & 1;            // j-half

    const int iw0 = ib * 128 + wy * 64;
    const int jw0 = jb * 128 + wx * 64;

    const int lr = lane & 15;           // row/col within 16x16 tile
    const int lk = lane >> 4;           // k-chunk (8 bf16)

    f32x4 acc[4][4];
#pragma unroll
    for (int m = 0; m < 4; ++m)
#pragma unroll
        for (int n = 0; n < 4; ++n) acc[m][n] = (f32x4){0.f, 0.f, 0.f, 0.f};

#pragma unroll
    for (int ks = 0; ks < 4; ++ks) {
        const int koff = ks * 32 + lk * 8;

        bf16x8 ah[4], al[4];
#pragma unroll
        for (int m = 0; m < 4; ++m) {
            const size_t ra = (size_t)(iw0 + m * 16 + lr) * C_CH + koff;
            ah[m] = *(const bf16x8*)&hi[ra];
            al[m] = *(const bf16x8*)&lo[ra];
        }
#pragma unroll
        for (int n = 0; n < 4; ++n) {
            const size_t rb = (size_t)(jw0 + n * 16 + lr) * C_CH + koff;
            const bf16x8 bh = *(const bf16x8*)&hi[rb];
            const bf16x8 bl = *(const bf16x8*)&lo[rb];
#pragma unroll
            for (int m = 0; m < 4; ++m) {
                acc[m][n] = __builtin_amdgcn_mfma_f32_16x16x32_bf16(ah[m], bh, acc[m][n], 0, 0, 0);
                acc[m][n] = __builtin_amdgcn_mfma_f32_16x16x32_bf16(ah[m], bl, acc[m][n], 0, 0, 0);
                acc[m][n] = __builtin_amdgcn_mfma_f32_16x16x32_bf16(al[m], bh, acc[m][n], 0, 0, 0);
            }
        }
    }

    // Epilogue. C/D layout: value r of lane l = C[iw0+m*16+(l>>4)*4+r][jw0+n*16+(l&15)]
    const int jslab = jw0 >> 6;         // 0..159
#pragma unroll
    for (int m = 0; m < 4; ++m) {
        float s0 = 0.f, s1 = 0.f, s2 = 0.f, s3 = 0.f;
#pragma unroll
        for (int n = 0; n < 4; ++n) {
            s0 += expf(acc[m][n][0]);
            s1 += expf(acc[m][n][1]);
            s2 += expf(acc[m][n][2]);
            s3 += expf(acc[m][n][3]);
        }
        float s[4] = {s0, s1, s2, s3};
#pragma unroll
        for (int r = 0; r < 4; ++r) {
            float v = s[r];
            v += __shfl_xor(v, 1, 64);
            v += __shfl_xor(v, 2, 64);
            v += __shfl_xor(v, 4, 64);
            v += __shfl_xor(v, 8, 64);
            if (lr == 0) {
                const int row = iw0 + m * 16 + lk * 4 + r;
                partial[(size_t)jslab * N_POS + row] = v;
            }
        }
    }
}

// ---------------------------------------------------------------------------
// Kernel 3a (REWORKED): per-row reduction with explicit 16-wide load batches
// (16 loads in flight per thread, 4 independent accumulators) + in-block
// LDS reduction of the per-row terms -> one partial sum per block.
// Single writer per block => deterministic.
__global__ __launch_bounds__(256) void rowred_kernel(
    const float* __restrict__ partial, float* __restrict__ bsum)
{
    const int t   = threadIdx.x;
    const int row = blockIdx.x * 256 + t;

    // P: 32 slabs, fully unrolled (32 independent loads in flight)
    float P = 0.f;
#pragma unroll
    for (int s = 0; s < NJSLAB_POS; ++s) P += partial[(size_t)s * N_POS + row];

    // Nv: 128 slabs in 8 batches of 16
    float a0 = 0.f, a1 = 0.f, a2 = 0.f, a3 = 0.f;
    for (int s0 = NJSLAB_POS; s0 < NJSLAB; s0 += 16) {
        float v[16];
#pragma unroll
        for (int i = 0; i < 16; ++i)
            v[i] = partial[(size_t)(s0 + i) * N_POS + row];
#pragma unroll
        for (int i = 0; i < 16; i += 4) {
            a0 += v[i]; a1 += v[i + 1]; a2 += v[i + 2]; a3 += v[i + 3];
        }
    }
    const float Nv = (a0 + a1) + (a2 + a3);

    const float p = P - 2.71828182845904523536f;   // remove self-sim exp(1)
    const float term = logf(p) - logf(p + Nv);

    __shared__ float red[256];
    red[t] = term;
    __syncthreads();
    for (int s = 128; s > 0; s >>= 1) {
        if (t < s) red[t] += red[t + s];
        __syncthreads();
    }
    if (t == 0) bsum[blockIdx.x] = red[0];
}

// Kernel 3b (trivial): sum the 8 block sums. Single wave, deterministic.
__global__ __launch_bounds__(64) void final_kernel(
    const float* __restrict__ bsum, float* __restrict__ out)
{
    if (threadIdx.x == 0) {
        float s = 0.f;
#pragma unroll
        for (int i = 0; i < N_POS / 256; ++i) s += bsum[i];
        out[0] = -s / (float)N_POS;
    }
}

// ---------------------------------------------------------------------------
extern "C" void kernel_launch(void* const* d_in, const int* in_sizes, int n_in,
                              void* d_out, int out_size, void* d_ws, size_t ws_size,
                              hipStream_t stream)
{
    const float* seg = (const float*)d_in[0];
    const int* pb = (const int*)d_in[1];
    const int* ph = (const int*)d_in[2];
    const int* pw = (const int*)d_in[3];
    const int* nb = (const int*)d_in[4];
    const int* nh = (const int*)d_in[5];
    const int* nw = (const int*)d_in[6];
    float* out = (float*)d_out;

    __hip_bfloat16* hi = (__hip_bfloat16*)d_ws;
    __hip_bfloat16* lo = hi + (size_t)N_ROWS * C_CH;
    float* partial = (float*)(lo + (size_t)N_ROWS * C_CH);
    float* bsum    = partial + (size_t)NJSLAB * N_POS;

    gather_norm_kernel<<<dim3((N_ROWS + 3) / 4), dim3(256), 0, stream>>>(
        seg, pb, ph, pw, nb, nh, nw, hi, lo);

    sim_mfma_kernel<<<dim3(NIB * NJB), dim3(256), 0, stream>>>(hi, lo, partial);

    rowred_kernel<<<dim3(N_POS / 256), dim3(256), 0, stream>>>(partial, bsum);
    final_kernel<<<dim3(1), dim3(64), 0, stream>>>(bsum, out);
}